// Round 1
// baseline (151.102 us; speedup 1.0000x reference)
//
#include <hip/hip_runtime.h>
#include <math.h>

// SMEFTNet forward: B=128, N=128, H=16.
// Pipeline: build_x0 -> proj(conv0) -> conv0 -> proj(conv1) -> conv1 -> readout
//
// conv layer math (per batch b, node i):
//   adj[i][j] = (|ang_i - ang_j|^2 <= 0.16)
//   cos/sin of relative angle between node i and j
//   feat = [h_i, h_j, h_j-h_i, cos, sin]  -> MLP(in->16 leaky0.01 ->17)
//   layer0 decomposed: u_i = h_i@(Wa-Wc), v_j = h_j@(Wb+Wc) precomputed per node
//   w[i][j] = pt_i*adj / sum_j(pt_i*adj)   (0 if denom<=0)
//   agg = sum_j w*m ; sw = sum_j w
//   out = [pt_i*sw, agg[0:16], rot(ang_i*sw by 2*pi*agg[16])]

#define BB 128
#define NN 128

__global__ void build_x0_kernel(const float* __restrict__ pt,
                                const float* __restrict__ ang,
                                float* __restrict__ x0, int total) {
    int i = blockIdx.x * blockDim.x + threadIdx.x;
    if (i >= total) return;
    float p = pt[i];
    float re = ang[2 * i], im = ang[2 * i + 1];
    float absz = sqrtf(re * re + im * im);
    float* o = x0 + 4 * (size_t)i;
    o[0] = p; o[1] = absz; o[2] = re; o[3] = im;
}

// Per-node layer-0 projections. One thread per (node, out-channel k).
__global__ void proj_kernel(const float* __restrict__ x, int F, int HIN,
                            const float* __restrict__ w0,
                            float* __restrict__ u, float* __restrict__ v,
                            int total_nodes) {
    int gid = blockIdx.x * blockDim.x + threadIdx.x;
    int n = gid >> 4, k = gid & 15;
    if (n >= total_nodes) return;
    const float* h = x + (size_t)n * F + 1;  // h = x[..., 1:-2]
    float su = 0.0f, sv = 0.0f;
    for (int c = 0; c < HIN; ++c) {
        float hv = h[c];
        float wa = w0[c * 16 + k];
        float wb = w0[(HIN + c) * 16 + k];
        float wc = w0[(2 * HIN + c) * 16 + k];
        su = fmaf(hv, wa - wc, su);
        sv = fmaf(hv, wb + wc, sv);
    }
    u[(size_t)n * 16 + k] = su;
    v[(size_t)n * 16 + k] = sv;
}

// One block per (b, i); 128 threads, thread tid handles pair (i, j=tid).
__global__ __launch_bounds__(128) void conv_kernel(
    const float* __restrict__ x, int F,
    const float* __restrict__ u, const float* __restrict__ v,
    const float* __restrict__ w0, int cos_row,
    const float* __restrict__ b0,
    const float* __restrict__ w1, const float* __restrict__ b1,
    float* __restrict__ y) {
    int ni = blockIdx.x;          // b*N + i
    int b = ni >> 7;
    int tid = threadIdx.x;        // j
    int nj = (b << 7) + tid;

    const float* xi = x + (size_t)ni * F;
    float pti = xi[0];
    float rei = xi[F - 2], imi = xi[F - 1];
    const float* xj = x + (size_t)nj * F;
    float rej = xj[F - 2], imj = xj[F - 1];

    float dre = rei - rej, dimv = imi - imj;
    float d2 = dre * dre + dimv * dimv;
    float adj = (d2 <= 0.16f) ? 1.0f : 0.0f;
    float r2i = rei * rei + imi * imi;
    float r2j = rej * rej + imj * imj;
    float nrm = fmaxf(sqrtf(r2i * r2j), 1e-12f);
    float inv = 1.0f / nrm;
    float cosv = (rei * rej + imi * imj) * inv;
    float sinv = (imi * rej - rei * imj) * inv;

    // per-pair MLP: z = u_i + v_j + cos*wc + sin*ws + b0 ; a = leaky(z) ; m = a@w1 + b1
    float m[17];
    {
        const float* ui = u + (size_t)ni * 16;
        const float* vj = v + (size_t)nj * 16;
        const float* wc = w0 + (size_t)cos_row * 16;
        const float* wsn = wc + 16;
#pragma unroll
        for (int t = 0; t < 17; ++t) m[t] = b1[t];
#pragma unroll
        for (int k = 0; k < 16; ++k) {
            float z = ui[k] + vj[k] + b0[k];
            z = fmaf(cosv, wc[k], z);
            z = fmaf(sinv, wsn[k], z);
            float a = (z >= 0.0f) ? z : 0.01f * z;
#pragma unroll
            for (int t = 0; t < 17; ++t) m[t] = fmaf(a, w1[k * 17 + t], m[t]);
        }
    }

    __shared__ float sred[2][18];

    // reduce msg -> denom
    float msg = pti * adj;
    float tot = msg;
#pragma unroll
    for (int off = 32; off; off >>= 1) tot += __shfl_xor(tot, off);
    if ((tid & 63) == 0) sred[tid >> 6][0] = tot;
    __syncthreads();
    float denom = sred[0][0] + sred[1][0];
    float w = (denom > 0.0f) ? (msg / denom) : 0.0f;
    __syncthreads();

    // weighted aggregate: 17 channels + sw
    float vals[18];
#pragma unroll
    for (int t = 0; t < 17; ++t) vals[t] = w * m[t];
    vals[17] = w;
#pragma unroll
    for (int t = 0; t < 18; ++t) {
        float s = vals[t];
#pragma unroll
        for (int off = 32; off; off >>= 1) s += __shfl_xor(s, off);
        vals[t] = s;
    }
    if ((tid & 63) == 0) {
#pragma unroll
        for (int t = 0; t < 18; ++t) sred[tid >> 6][t] = vals[t];
    }
    __syncthreads();
    if (tid == 0) {
        float agg[17];
#pragma unroll
        for (int t = 0; t < 17; ++t) agg[t] = sred[0][t] + sred[1][t];
        float sw = sred[0][17] + sred[1][17];
        float agg_pt = pti * sw;
        float are = rei * sw, aim = imi * sw;
        float gamma = agg[16];
        float th = 6.283185307179586f * gamma;
        float c = cosf(th), s = sinf(th);
        float re2 = c * are - s * aim;
        float im2 = s * are + c * aim;
        float* yo = y + (size_t)ni * 19;
        yo[0] = agg_pt;
#pragma unroll
        for (int t = 0; t < 16; ++t) yo[1 + t] = agg[t];
        yo[17] = re2;
        yo[18] = im2;
    }
}

// One block per batch b; 128 threads (one per node).
__global__ __launch_bounds__(128) void readout_kernel(
    const float* __restrict__ y,   // (B,N,19)
    const float* __restrict__ w0, const float* __restrict__ b0,  // (16,32),(32)
    const float* __restrict__ w1, const float* __restrict__ b1,  // (32,32),(32)
    const float* __restrict__ w2, const float* __restrict__ b2,  // (32,1),(1)
    float* __restrict__ out) {
    int b = blockIdx.x;
    int tid = threadIdx.x;
    const float* yn = y + ((size_t)b * NN + tid) * 19;
    float ptf = yn[0];

    __shared__ float sred[2][18];
    __shared__ float xg[18];
    __shared__ float h1s[32];

    float tot = ptf;
#pragma unroll
    for (int off = 32; off; off >>= 1) tot += __shfl_xor(tot, off);
    if ((tid & 63) == 0) sred[tid >> 6][0] = tot;
    __syncthreads();
    float denom = sred[0][0] + sred[1][0];
    float wj = (denom > 0.0f) ? (ptf / denom) : 0.0f;
    __syncthreads();

    float vals[18];
#pragma unroll
    for (int f = 0; f < 18; ++f) vals[f] = wj * yn[1 + f];
#pragma unroll
    for (int f = 0; f < 18; ++f) {
        float s = vals[f];
#pragma unroll
        for (int off = 32; off; off >>= 1) s += __shfl_xor(s, off);
        vals[f] = s;
    }
    if ((tid & 63) == 0) {
#pragma unroll
        for (int f = 0; f < 18; ++f) sred[tid >> 6][f] = vals[f];
    }
    __syncthreads();
    if (tid < 18) xg[tid] = sred[0][tid] + sred[1][tid];
    __syncthreads();

    if (tid < 32) {
        float h = b0[tid];
#pragma unroll
        for (int k = 0; k < 16; ++k) h = fmaf(xg[k], w0[k * 32 + tid], h);
        h = (h >= 0.0f) ? h : 0.01f * h;
        h1s[tid] = h;
    }
    __syncthreads();
    if (tid < 32) {
        float h = b1[tid];
#pragma unroll
        for (int k = 0; k < 32; ++k) h = fmaf(h1s[k], w1[k * 32 + tid], h);
        h = (h >= 0.0f) ? h : 0.01f * h;
        float p = h * w2[tid];
#pragma unroll
        for (int off = 16; off; off >>= 1) p += __shfl_xor(p, off, 32);
        if (tid == 0) {
            float logit = p + b2[0];
            out[b * 3 + 0] = 1.0f / (1.0f + expf(-logit));
            out[b * 3 + 1] = xg[16];
            out[b * 3 + 2] = xg[17];
        }
    }
}

extern "C" void kernel_launch(void* const* d_in, const int* in_sizes, int n_in,
                              void* d_out, int out_size, void* d_ws, size_t ws_size,
                              hipStream_t stream) {
    const float* pt    = (const float*)d_in[0];
    const float* ang   = (const float*)d_in[1];
    const float* c0_w0 = (const float*)d_in[2];
    const float* c0_b0 = (const float*)d_in[3];
    const float* c0_w1 = (const float*)d_in[4];
    const float* c0_b1 = (const float*)d_in[5];
    const float* c1_w0 = (const float*)d_in[6];
    const float* c1_b0 = (const float*)d_in[7];
    const float* c1_w1 = (const float*)d_in[8];
    const float* c1_b1 = (const float*)d_in[9];
    const float* r_w0  = (const float*)d_in[10];
    const float* r_b0  = (const float*)d_in[11];
    const float* r_w1  = (const float*)d_in[12];
    const float* r_b1  = (const float*)d_in[13];
    const float* r_w2  = (const float*)d_in[14];
    const float* r_b2  = (const float*)d_in[15];
    float* out = (float*)d_out;
    float* ws = (float*)d_ws;

    const int BN = BB * NN;
    float* x0 = ws;                 // BN*4
    float* y0 = x0 + (size_t)BN * 4;   // BN*19
    float* uu = y0 + (size_t)BN * 19;  // BN*16
    float* vv = uu + (size_t)BN * 16;  // BN*16
    float* y1 = vv + (size_t)BN * 16;  // BN*19

    hipLaunchKernelGGL(build_x0_kernel, dim3(BN / 256), dim3(256), 0, stream,
                       pt, ang, x0, BN);
    hipLaunchKernelGGL(proj_kernel, dim3(BN * 16 / 256), dim3(256), 0, stream,
                       x0, 4, 1, c0_w0, uu, vv, BN);
    hipLaunchKernelGGL(conv_kernel, dim3(BN), dim3(128), 0, stream,
                       x0, 4, uu, vv, c0_w0, 3, c0_b0, c0_w1, c0_b1, y0);
    hipLaunchKernelGGL(proj_kernel, dim3(BN * 16 / 256), dim3(256), 0, stream,
                       y0, 19, 16, c1_w0, uu, vv, BN);
    hipLaunchKernelGGL(conv_kernel, dim3(BN), dim3(128), 0, stream,
                       y0, 19, uu, vv, c1_w0, 48, c1_b0, c1_w1, c1_b1, y1);
    hipLaunchKernelGGL(readout_kernel, dim3(BB), dim3(128), 0, stream,
                       y1, r_w0, r_b0, r_w1, r_b1, r_w2, r_b2, out);
}

// Round 2
// 37.120 us; speedup vs baseline: 4.0707x; 4.0707x over previous
//
#include <hip/hip_runtime.h>
#include <math.h>

// SMEFTNet forward, restructured. B=128, N=128, H=16.
//
// Key algebra:
//   w[i][j] = pt_i*adj/(pt_i*deg_i) = adj/deg_i ; diagonal adj=1 => deg>=1, sw=1
//   agg[t]  = (1/deg) * sum_k (sum_j adj*a_jk) * w1[k][t] + b1[t]   (2nd layer per NODE)
//   layer0 h = [absz] (rank-1) => no proj arrays needed for conv0
//   conv0 epilogue fuses proj for conv1: u1b = b0' + h1@(Wa-Wc), v1 = h1@(Wb+Wc)
//
// Reduction over j uses DPP add tree (pure VALU, no DS pipe pressure):
//   quad_perm(1,0,3,2), quad_perm(2,3,0,1), row_shr:4, row_shr:8,
//   row_bcast15, row_bcast31 -> total in lane 63 -> readlane to SGPR.

#define BB 128
#define NN 128
#define BN (BB * NN)
#define TWO_PI_F 6.283185307179586f

template <int CTRL>
__device__ __forceinline__ float dpp_add(float x) {
    int t = __builtin_amdgcn_update_dpp(0, __float_as_int(x), CTRL, 0xF, 0xF, true);
    return x + __int_as_float(t);
}

// Sum across 64 lanes; returns wave-uniform (SGPR) value.
__device__ __forceinline__ float wave_sum64(float x) {
    x = dpp_add<0xB1>(x);   // quad_perm [1,0,3,2]  (xor 1)
    x = dpp_add<0x4E>(x);   // quad_perm [2,3,0,1]  (xor 2)
    x = dpp_add<0x114>(x);  // row_shr:4
    x = dpp_add<0x118>(x);  // row_shr:8   -> lane15 of each row16 = row sum
    x = dpp_add<0x142>(x);  // row_bcast15 -> lane31/63 pick up prev row
    x = dpp_add<0x143>(x);  // row_bcast31 -> lane63 = full sum
    return __int_as_float(__builtin_amdgcn_readlane(__float_as_int(x), 63));
}

// One wave per node (i); lanes handle j = lane and lane+64. 4 waves/block.
template <int L>
__global__ __launch_bounds__(256) void conv_kernel(
    const float* __restrict__ ang,   // (BN,2): input ang (L0) or ang1 (L1)
    const float* __restrict__ u,     // L1: u1b (BN,16)
    const float* __restrict__ v,     // L1: v1  (BN,16)
    const float* __restrict__ w0,    // conv layer-0 weights: L0 (5,16), L1 (50,16)
    const float* __restrict__ b0,    // L0 only (L1 folded into u)
    const float* __restrict__ w1,    // (16,17)
    const float* __restrict__ b1,    // (17)
    const float* __restrict__ nw0,   // L0 only: c1_w0 (50,16) for fused proj
    const float* __restrict__ nb0,   // L0 only: c1_b0 (16)
    float* __restrict__ out_u,       // L0: u1b
    float* __restrict__ out_v,       // L0: v1
    float* __restrict__ out_ang,     // L0: ang1
    float* __restrict__ y)           // L1: (BN,18) = [h(16), re2, im2]
{
    const int lane = threadIdx.x & 63;
    const int wid  = threadIdx.x >> 6;
    const int ni   = __builtin_amdgcn_readfirstlane(blockIdx.x * 4 + wid);
    const int base = ni & ~(NN - 1);

    const float rei = ang[2 * ni], imi = ang[2 * ni + 1];
    const float r2i = rei * rei + imi * imi;

    constexpr int cosrow = (L == 0) ? 3 : 48;

    // wave-uniform layer-0-row precompute
    float u0b[16];
    float q0[16];
    if constexpr (L == 0) {
        float abszi = __builtin_amdgcn_sqrtf(r2i);
        #pragma unroll
        for (int k = 0; k < 16; ++k) {
            u0b[k] = fmaf(abszi, w0[k] - w0[32 + k], b0[k]);  // Wa-Wc scaled + b0
            q0[k]  = w0[16 + k] + w0[32 + k];                 // Wb+Wc
        }
    } else {
        #pragma unroll
        for (int k = 0; k < 16; ++k) u0b[k] = u[ni * 16 + k];  // uniform -> s_load
    }

    float A[16];
    #pragma unroll
    for (int k = 0; k < 16; ++k) A[k] = 0.0f;
    int deg = 0;

    #pragma unroll
    for (int jj = 0; jj < 2; ++jj) {
        const int nj = base + lane + jj * 64;
        const float rej = ang[2 * nj], imj = ang[2 * nj + 1];

        const float dre = rei - rej, dim = imi - imj;
        const float d2 = dre * dre + dim * dim;
        const bool isadj = (d2 <= 0.16f);
        deg += (int)__popcll(__ballot(isadj));
        const float adjf = isadj ? 1.0f : 0.0f;

        const float r2j = rej * rej + imj * imj;
        const float inv = fminf(rsqrtf(r2i * r2j), 1e12f);
        const float cosv = fmaf(rei, rej, imi * imj) * inv;
        const float sinv = fmaf(imi, rej, -(rei * imj)) * inv;

        float abszj = 0.0f;
        float vj[16];
        if constexpr (L == 0) {
            abszj = __builtin_amdgcn_sqrtf(r2j);
        } else {
            const float4* vp = (const float4*)(v + (size_t)nj * 16);
            float4 a0 = vp[0], a1 = vp[1], a2 = vp[2], a3 = vp[3];
            vj[0] = a0.x; vj[1] = a0.y; vj[2]  = a0.z; vj[3]  = a0.w;
            vj[4] = a1.x; vj[5] = a1.y; vj[6]  = a1.z; vj[7]  = a1.w;
            vj[8] = a2.x; vj[9] = a2.y; vj[10] = a2.z; vj[11] = a2.w;
            vj[12] = a3.x; vj[13] = a3.y; vj[14] = a3.z; vj[15] = a3.w;
        }

        #pragma unroll
        for (int k = 0; k < 16; ++k) {
            float z;
            if constexpr (L == 0) z = fmaf(abszj, q0[k], u0b[k]);
            else                  z = u0b[k] + vj[k];
            z = fmaf(cosv, w0[cosrow * 16 + k], z);
            z = fmaf(sinv, w0[(cosrow + 1) * 16 + k], z);
            float a = fmaxf(z, 0.01f * z);       // leaky relu 0.01
            A[k] = fmaf(a, adjf, A[k]);          // masked accumulate
        }
    }

    // cross-lane reduce: 16 channels -> wave-uniform SGPR values
    float Ak[16];
    #pragma unroll
    for (int k = 0; k < 16; ++k) Ak[k] = wave_sum64(A[k]);
    const float invdeg = 1.0f / (float)deg;

    // per-node second MLP layer: lanes 0..16 each own one output channel
    float aggv = 0.0f;
    if (lane < 17) {
        float s = 0.0f;
        #pragma unroll
        for (int k = 0; k < 16; ++k) s = fmaf(Ak[k], w1[k * 17 + lane], s);
        aggv = fmaf(s, invdeg, b1[lane]);
    }

    __shared__ float h1s[4][16];

    if constexpr (L == 0) {
        if (lane < 16) h1s[wid][lane] = aggv;       // h for next layer
        if (lane == 16) {                            // gamma -> rotated ang
            float th = TWO_PI_F * aggv;
            float cs = cosf(th), sn = sinf(th);
            out_ang[2 * ni]     = cs * rei - sn * imi;
            out_ang[2 * ni + 1] = sn * rei + cs * imi;
        }
        __syncthreads();
        // fused proj for conv1: lanes 0..15 -> u1b[k], lanes 16..31 -> v1[k]
        if (lane < 32) {
            const int k = lane & 15;
            const bool isU = lane < 16;
            const int off = isU ? 0 : 256;           // Wa block vs Wb block
            const float sgn = isU ? -1.0f : 1.0f;    // -Wc vs +Wc
            float acc = isU ? nb0[k] : 0.0f;
            #pragma unroll
            for (int c = 0; c < 16; ++c) {
                float wa  = nw0[off + c * 16 + k];
                float wcv = nw0[512 + c * 16 + k];
                acc = fmaf(h1s[wid][c], fmaf(sgn, wcv, wa), acc);
            }
            if (isU) out_u[ni * 16 + k] = acc;
            else     out_v[ni * 16 + k] = acc;
        }
    } else {
        if (lane < 16) y[ni * 18 + lane] = aggv;
        if (lane == 16) {
            float th = TWO_PI_F * aggv;
            float cs = cosf(th), sn = sinf(th);
            y[ni * 18 + 16] = cs * rei - sn * imi;
            y[ni * 18 + 17] = sn * rei + cs * imi;
        }
    }
}

// One block per batch b; 128 threads (one per node).
__global__ __launch_bounds__(128) void readout_kernel(
    const float* __restrict__ pt,  // (B,N) original pt (ptf == pt since sw==1)
    const float* __restrict__ y,   // (B,N,18)
    const float* __restrict__ w0, const float* __restrict__ b0,  // (16,32),(32)
    const float* __restrict__ w1, const float* __restrict__ b1,  // (32,32),(32)
    const float* __restrict__ w2, const float* __restrict__ b2,  // (32,1),(1)
    float* __restrict__ out) {
    int b = blockIdx.x;
    int tid = threadIdx.x;
    int n = b * NN + tid;
    float ptf = pt[n];
    const float* yn = y + (size_t)n * 18;

    __shared__ float sred[2][18];
    __shared__ float xg[18];
    __shared__ float h1s[32];

    float tot = ptf;
#pragma unroll
    for (int off = 32; off; off >>= 1) tot += __shfl_xor(tot, off);
    if ((tid & 63) == 0) sred[tid >> 6][0] = tot;
    __syncthreads();
    float denom = sred[0][0] + sred[1][0];
    float wj = (denom > 0.0f) ? (ptf / denom) : 0.0f;
    __syncthreads();

    float vals[18];
#pragma unroll
    for (int f = 0; f < 18; ++f) vals[f] = wj * yn[f];
#pragma unroll
    for (int f = 0; f < 18; ++f) {
        float s = vals[f];
#pragma unroll
        for (int off = 32; off; off >>= 1) s += __shfl_xor(s, off);
        vals[f] = s;
    }
    if ((tid & 63) == 0) {
#pragma unroll
        for (int f = 0; f < 18; ++f) sred[tid >> 6][f] = vals[f];
    }
    __syncthreads();
    if (tid < 18) xg[tid] = sred[0][tid] + sred[1][tid];
    __syncthreads();

    if (tid < 32) {
        float h = b0[tid];
#pragma unroll
        for (int k = 0; k < 16; ++k) h = fmaf(xg[k], w0[k * 32 + tid], h);
        h = (h >= 0.0f) ? h : 0.01f * h;
        h1s[tid] = h;
    }
    __syncthreads();
    if (tid < 32) {
        float h = b1[tid];
#pragma unroll
        for (int k = 0; k < 32; ++k) h = fmaf(h1s[k], w1[k * 32 + tid], h);
        h = (h >= 0.0f) ? h : 0.01f * h;
        float p = h * w2[tid];
#pragma unroll
        for (int off = 16; off; off >>= 1) p += __shfl_xor(p, off, 32);
        if (tid == 0) {
            float logit = p + b2[0];
            out[b * 3 + 0] = 1.0f / (1.0f + expf(-logit));
            out[b * 3 + 1] = xg[16];
            out[b * 3 + 2] = xg[17];
        }
    }
}

extern "C" void kernel_launch(void* const* d_in, const int* in_sizes, int n_in,
                              void* d_out, int out_size, void* d_ws, size_t ws_size,
                              hipStream_t stream) {
    const float* pt    = (const float*)d_in[0];
    const float* ang   = (const float*)d_in[1];
    const float* c0_w0 = (const float*)d_in[2];
    const float* c0_b0 = (const float*)d_in[3];
    const float* c0_w1 = (const float*)d_in[4];
    const float* c0_b1 = (const float*)d_in[5];
    const float* c1_w0 = (const float*)d_in[6];
    const float* c1_b0 = (const float*)d_in[7];
    const float* c1_w1 = (const float*)d_in[8];
    const float* c1_b1 = (const float*)d_in[9];
    const float* r_w0  = (const float*)d_in[10];
    const float* r_b0  = (const float*)d_in[11];
    const float* r_w1  = (const float*)d_in[12];
    const float* r_b1  = (const float*)d_in[13];
    const float* r_w2  = (const float*)d_in[14];
    const float* r_b2  = (const float*)d_in[15];
    float* out = (float*)d_out;
    float* ws = (float*)d_ws;

    float* u1b  = ws;                       // BN*16
    float* v1   = u1b + (size_t)BN * 16;    // BN*16
    float* ang1 = v1 + (size_t)BN * 16;     // BN*2
    float* y1   = ang1 + (size_t)BN * 2;    // BN*18

    hipLaunchKernelGGL((conv_kernel<0>), dim3(BN / 4), dim3(256), 0, stream,
                       ang, (const float*)nullptr, (const float*)nullptr,
                       c0_w0, c0_b0, c0_w1, c0_b1,
                       c1_w0, c1_b0, u1b, v1, ang1, (float*)nullptr);
    hipLaunchKernelGGL((conv_kernel<1>), dim3(BN / 4), dim3(256), 0, stream,
                       ang1, u1b, v1,
                       c1_w0, (const float*)nullptr, c1_w1, c1_b1,
                       (const float*)nullptr, (const float*)nullptr,
                       (float*)nullptr, (float*)nullptr, (float*)nullptr, y1);
    hipLaunchKernelGGL(readout_kernel, dim3(BB), dim3(128), 0, stream,
                       pt, y1, r_w0, r_b0, r_w1, r_b1, r_w2, r_b2, out);
}